// Round 2
// baseline (296.921 us; speedup 1.0000x reference)
//
#include <hip/hip_runtime.h>
#include <hip/hip_bf16.h>
#include <math.h>

// Problem constants
#define B_ 4
#define L_ 4096
#define E_ 1024
#define H_ 16
#define D_ 64
#define N_ 64          // B*H heads
#define D2_ 128        // feature dim 2*D
#define EPS_ 1e-6f

#define CH_ 8              // phase1 L-chunks
#define LC_ (L_ / CH_)     // 512 rows per phase1 block
#define LT_ 64             // rows per LDS stage
#define NST_ (LC_ / LT_)   // 8 stages

#define DANG_ 3.83495197e-4f  // 0.5*pi/L

typedef short short8 __attribute__((ext_vector_type(8)));
typedef float f32x4 __attribute__((ext_vector_type(4)));
typedef unsigned int u32;
typedef unsigned short u16;

static __device__ __forceinline__ u32 pack2bf(float a, float b) {
  union { __hip_bfloat16 h; u16 s; } x, y;
  x.h = __float2bfloat16(a);
  y.h = __float2bfloat16(b);
  return (u32)x.s | ((u32)y.s << 16);
}

static __device__ __forceinline__ short bf1(float a) {
  union { __hip_bfloat16 h; short s; } x;
  x.h = __float2bfloat16(a);
  return x.s;
}

// async 16B global -> LDS (wave-uniform LDS base + lane*16)
static __device__ __forceinline__ void gld16(const void* g, void* l) {
  __builtin_amdgcn_global_load_lds(
      (const __attribute__((address_space(1))) unsigned int*)g,
      (__attribute__((address_space(3))) unsigned int*)l, 16, 0, 0);
}

// ---------------------------------------------------------------------------
// Phase 1 (MFMA): partial kv[d][m] = sum_l k_[l][d] * v[l][m], ksum[d]=sum k_
// Software-pipelined register prefetch (unchanged structure from prev round;
// launch_bounds 2->3 waves/EU for more cross-block barrier overlap).
// ---------------------------------------------------------------------------
__global__ __launch_bounds__(256, 3) void phase1_mfma(
    const float* __restrict__ k, const float* __restrict__ v,
    const float* __restrict__ mask,
    float* __restrict__ part_kv, float* __restrict__ part_ks) {
  __shared__ __align__(16) u16 ka[D2_ * 72];
  __shared__ __align__(16) u16 vt[D_ * 72];

  const int bid = blockIdx.x;
  const int n = bid & 63;
  const int ch = bid >> 6;
  const int b = n >> 4;
  const int h = n & 15;
  const int t = threadIdx.x;
  const int wv = t >> 6;
  const int lane = t & 63;
  const int c_lo = lane & 15;
  const int lp = lane >> 4;       // quad
  const int c = wv * 16 + c_lo;   // staging column 0..63

  f32x4 acc[2][4];
#pragma unroll
  for (int i = 0; i < 2; ++i)
#pragma unroll
    for (int j = 0; j < 4; ++j) acc[i][j] = (f32x4)0.f;
  float kss = 0.f, ksc = 0.f;

  const int l0 = ch * LC_;
  const size_t gb0 = (size_t)(b * L_ + l0) * E_ + h * 64 + c;

  // double-buffered prefetch registers (static indexing only)
  float Ak0[8], Ak1[8], Av0[8], Av1[8], Am;
  float Bk0[8], Bk1[8], Bv0[8], Bv1[8], Bm;

#define P1_PREF(Rk0, Rk1, Rv0, Rv1, Rm, S)                                   \
  do {                                                                       \
    const size_t gs_ = gb0 + (size_t)(S) * (LT_ * E_);                       \
    _Pragma("unroll") for (int i_ = 0; i_ < 8; ++i_) {                       \
      const size_t g0_ = gs_ + (size_t)(8 * i_ + 2 * lp) * E_;               \
      Rk0[i_] = k[g0_];                                                      \
      Rk1[i_] = k[g0_ + E_];                                                 \
      Rv0[i_] = v[g0_];                                                      \
      Rv1[i_] = v[g0_ + E_];                                                 \
    }                                                                        \
    Rm = mask[(size_t)b * L_ + l0 + (S) * LT_ + lane];                       \
  } while (0)

#define P1_STAGE(Rk0, Rk1, Rv0, Rv1, Rm, S)                                  \
  do {                                                                       \
    const int lb_ = l0 + (S) * LT_;                                          \
    _Pragma("unroll") for (int i_ = 0; i_ < 8; ++i_) {                       \
      const int l_ = 8 * i_ + 2 * lp;                                        \
      const float m0_ = __shfl(Rm, l_);                                      \
      const float m1_ = __shfl(Rm, l_ + 1);                                  \
      float s0_, c0_, s1_, c1_;                                              \
      __sincosf((float)(lb_ + l_ + 1) * DANG_, &s0_, &c0_);                  \
      __sincosf((float)(lb_ + l_ + 2) * DANG_, &s1_, &c1_);                  \
      const float kr0_ = fmaxf(Rk0[i_], 0.f) * m0_;                          \
      const float kr1_ = fmaxf(Rk1[i_], 0.f) * m1_;                          \
      const float ks0_ = kr0_ * s0_, ks1_ = kr1_ * s1_;                      \
      const float kc0_ = kr0_ * c0_, kc1_ = kr1_ * c1_;                      \
      const int li_ = 4 * i_ + lp;                                           \
      ((u32*)ka)[c * 36 + li_] = pack2bf(ks0_, ks1_);                        \
      ((u32*)ka)[(c + 64) * 36 + li_] = pack2bf(kc0_, kc1_);                 \
      ((u32*)vt)[c * 36 + li_] = pack2bf(Rv0[i_] * m0_, Rv1[i_] * m1_);      \
      kss += ks0_ + ks1_;                                                    \
      ksc += kc0_ + kc1_;                                                    \
    }                                                                        \
  } while (0)

#define P1_MMA()                                                             \
  do {                                                                       \
    _Pragma("unroll") for (int kk_ = 0; kk_ < 2; ++kk_) {                    \
      const int colo_ = kk_ * 32 + lp * 8;                                   \
      short8 af_[2], bf_[4];                                                 \
      _Pragma("unroll") for (int dt_ = 0; dt_ < 2; ++dt_)                    \
          af_[dt_] =                                                         \
              *(const short8*)&ka[(wv * 32 + dt_ * 16 + c_lo) * 72 + colo_]; \
      _Pragma("unroll") for (int mt_ = 0; mt_ < 4; ++mt_)                    \
          bf_[mt_] = *(const short8*)&vt[(mt_ * 16 + c_lo) * 72 + colo_];    \
      _Pragma("unroll") for (int dt_ = 0; dt_ < 2; ++dt_)                    \
          _Pragma("unroll") for (int mt_ = 0; mt_ < 4; ++mt_)                \
              acc[dt_][mt_] = __builtin_amdgcn_mfma_f32_16x16x32_bf16(       \
                  af_[dt_], bf_[mt_], acc[dt_][mt_], 0, 0, 0);               \
    }                                                                        \
  } while (0)

  P1_PREF(Ak0, Ak1, Av0, Av1, Am, 0);
  for (int st = 0; st < NST_; st += 2) {
    __syncthreads();  // previous MFMA readers done -> LDS writable
    P1_PREF(Bk0, Bk1, Bv0, Bv1, Bm, st + 1);  // issue next-stage loads early
    P1_STAGE(Ak0, Ak1, Av0, Av1, Am, st);
    __syncthreads();
    P1_MMA();
    __syncthreads();
    if (st + 2 < NST_) P1_PREF(Ak0, Ak1, Av0, Av1, Am, st + 2);
    P1_STAGE(Bk0, Bk1, Bv0, Bv1, Bm, st + 1);
    __syncthreads();
    P1_MMA();
  }

  // write partial kv (fp32). C layout: row(d)=quad*4+r, col(m)=lane&15
  const size_t pbase = (size_t)(ch * N_ + n) * (D2_ * D_);
#pragma unroll
  for (int dt = 0; dt < 2; ++dt) {
    const int d = wv * 32 + dt * 16 + lp * 4;
#pragma unroll
    for (int mt = 0; mt < 4; ++mt) {
      const int mcol = mt * 16 + c_lo;
#pragma unroll
      for (int r = 0; r < 4; ++r)
        part_kv[pbase + (size_t)(d + r) * D_ + mcol] = acc[dt][mt][r];
    }
  }
  // ksum partials: reduce over lp groups (lanes +-16, +-32)
  kss += __shfl_xor(kss, 16); kss += __shfl_xor(kss, 32);
  ksc += __shfl_xor(ksc, 16); ksc += __shfl_xor(ksc, 32);
  if (lp == 0) {
    part_ks[(size_t)(ch * N_ + n) * D2_ + c] = kss;
    part_ks[(size_t)(ch * N_ + n) * D2_ + c + 64] = ksc;
  }
}

// ---------------------------------------------------------------------------
// Reduce: sum chunk partials; emit kvT[n][m][d] bf16 + ksum fp32.
// ---------------------------------------------------------------------------
__global__ __launch_bounds__(256) void reduce_t(
    const float* __restrict__ part_kv, const float* __restrict__ part_ks,
    u16* __restrict__ kvt, float* __restrict__ ks) {
  __shared__ __align__(16) float tsh[16 * 68];
  const int bid = blockIdx.x;
  const int n = bid >> 3;
  const int sl = bid & 7;
  const int t = threadIdx.x;

  const int e0 = sl * 1024 + t * 4;  // covers d=sl*16..+16, m=0..63
  f32x4 s = (f32x4)0.f;
#pragma unroll
  for (int cc = 0; cc < CH_; ++cc)
    s += *(const f32x4*)&part_kv[(size_t)(cc * N_ + n) * (D2_ * D_) + e0];
  *(f32x4*)&tsh[(t >> 4) * 68 + (t & 15) * 4] = s;

  if (sl == 0 && t < D2_) {
    float ss = 0.f;
#pragma unroll
    for (int cc = 0; cc < CH_; ++cc)
      ss += part_ks[(size_t)(cc * N_ + n) * D2_ + t];
    ks[n * D2_ + t] = ss;
  }
  __syncthreads();

  // transpose out: thread -> m = t>>2, 4 consecutive d
  const int m = t >> 2;
  const int d4 = (t & 3) * 4;
  const u32 lo = pack2bf(tsh[(d4 + 0) * 68 + m], tsh[(d4 + 1) * 68 + m]);
  const u32 hi = pack2bf(tsh[(d4 + 2) * 68 + m], tsh[(d4 + 3) * 68 + m]);
  uint2 pk; pk.x = lo; pk.y = hi;
  *(uint2*)&kvt[(size_t)n * (D2_ * D_) + (size_t)m * D2_ + sl * 16 + d4] = pk;
}

// ---------------------------------------------------------------------------
// Phase 2 (MFMA): out[l][m] = z[l] * sum_d q_[l][d] * kv[d][m]
// Async-staged: raw f32 q (16KB) + bf16 kvt (16KB) pulled into LDS via
// global_load_lds width=16 (8 insts/wave, zero staging VGPRs). Granules are
// XOR-swizzled (g ^= row&15) on the GLOBAL source and on the LDS reads
// (both-sides rule) -> 2-way max bank aliasing instead of 16-way.
// A-fragments built in-register from raw q rows (one sincos per lane).
// z via 5th B-fragment whose column 0 is ksum.
// ---------------------------------------------------------------------------
__global__ __launch_bounds__(256, 4) void phase2_mfma(
    const float* __restrict__ q, const u16* __restrict__ kvt,
    const float* __restrict__ ks, float* __restrict__ out) {
  __shared__ __align__(16) float qsh[64 * 64];   // raw q, swizzled granules
  __shared__ __align__(16) u16 kbsh[64 * 128];   // kvt rows, swizzled granules

  const int bid = blockIdx.x;
  const int n = bid & 63;
  const int lc = bid >> 6;
  const int b = n >> 4, h = n & 15;
  const int t = threadIdx.x;
  const int wv = t >> 6, lane = t & 63;
  const int c_lo = lane & 15, quad = lane >> 4;
  const int l0 = lc * 64;

  // ---- async staging: wave wv owns rows [wv*16, wv*16+16) of both tiles ----
  const float* qbase = q + (size_t)(b * L_ + l0) * E_ + h * 64;
  const u16* kvbase = kvt + (size_t)n * (D2_ * D_);
  const int rsub = lane >> 4;  // 0..3 rows within one 1KB instruction
  const int g = lane & 15;     // physical 16B granule within row
#pragma unroll
  for (int j = 0; j < 4; ++j) {
    const int r = wv * 16 + j * 4 + rsub;
    gld16(qbase + (size_t)r * E_ + ((g ^ (r & 15)) << 2),
          qsh + (wv * 16 + j * 4) * 64);
    gld16(kvbase + (size_t)r * D2_ + ((g ^ (r & 15)) << 3),
          kbsh + (wv * 16 + j * 4) * 128);
  }

  // ---- ksum B-fragments (register path, col 0 = ksum) ----
  const float* ksn = ks + n * D2_;
  short8 bks[4];
#pragma unroll
  for (int kk = 0; kk < 4; ++kk) {
    const f32x4 ka_ = *(const f32x4*)(ksn + kk * 32 + quad * 8);
    const f32x4 kb_ = *(const f32x4*)(ksn + kk * 32 + quad * 8 + 4);
    short8 tt = {0, 0, 0, 0, 0, 0, 0, 0};
    if (c_lo == 0) {
#pragma unroll
      for (int j = 0; j < 4; ++j) {
        tt[j] = bf1(ka_[j]);
        tt[j + 4] = bf1(kb_[j]);
      }
    }
    bks[kk] = tt;
  }

  const int row = wv * 16 + c_lo;  // the A-row this lane feeds
  float sv, cv;
  __sincosf((float)(l0 + row + 1) * DANG_, &sv, &cv);

  __syncthreads();  // drains vmcnt(0): all global_load_lds landed

  // ---- A-fragments from raw q LDS (swizzled reads, 2-way max) ----
  const float* qrow = qsh + row * 64;
  const int sw = row & 15;
  const f32x4 a0 = *(const f32x4*)(qrow + (((2 * quad) ^ sw) << 2));
  const f32x4 a1 = *(const f32x4*)(qrow + (((2 * quad + 1) ^ sw) << 2));
  const f32x4 a2 = *(const f32x4*)(qrow + (((8 + 2 * quad) ^ sw) << 2));
  const f32x4 a3 = *(const f32x4*)(qrow + (((9 + 2 * quad) ^ sw) << 2));

  short8 af[4];
#pragma unroll
  for (int j = 0; j < 4; ++j) {
    const float x0 = fmaxf(a0[j], 0.f);
    const float x1 = fmaxf(a1[j], 0.f);
    const float x2 = fmaxf(a2[j], 0.f);
    const float x3 = fmaxf(a3[j], 0.f);
    af[0][j] = bf1(x0 * sv); af[0][j + 4] = bf1(x1 * sv);
    af[1][j] = bf1(x2 * sv); af[1][j + 4] = bf1(x3 * sv);
    af[2][j] = bf1(x0 * cv); af[2][j + 4] = bf1(x1 * cv);
    af[3][j] = bf1(x2 * cv); af[3][j + 4] = bf1(x3 * cv);
  }

  f32x4 acc[4];
#pragma unroll
  for (int mt = 0; mt < 4; ++mt) acc[mt] = (f32x4)0.f;
  f32x4 acc5 = (f32x4)0.f;

#pragma unroll
  for (int kk = 0; kk < 4; ++kk) {
#pragma unroll
    for (int mt = 0; mt < 4; ++mt) {
      const int m = mt * 16 + c_lo;
      const short8 bfr = *(const short8*)
          &kbsh[m * 128 + (((kk * 4 + quad) ^ (m & 15)) << 3)];
      acc[mt] = __builtin_amdgcn_mfma_f32_16x16x32_bf16(af[kk], bfr, acc[mt], 0, 0, 0);
    }
    acc5 = __builtin_amdgcn_mfma_f32_16x16x32_bf16(af[kk], bks[kk], acc5, 0, 0, 0);
  }

  // epilogue: z from acc5 col 0 (lane quad*16), scale, store
#pragma unroll
  for (int r = 0; r < 4; ++r) {
    const float den = __shfl(acc5[r], quad * 16);
    const float z = 1.f / fmaxf(den, EPS_);
    const int gl = l0 + wv * 16 + quad * 4 + r;
    const size_t ob = (size_t)n * (L_ * D_) + (size_t)gl * D_;
#pragma unroll
    for (int mt = 0; mt < 4; ++mt)
      out[ob + mt * 16 + c_lo] = acc[mt][r] * z;
  }
}

// ---------------------------------------------------------------------------
extern "C" void kernel_launch(void* const* d_in, const int* in_sizes, int n_in,
                              void* d_out, int out_size, void* d_ws,
                              size_t ws_size, hipStream_t stream) {
  const float* q = (const float*)d_in[0];
  const float* k = (const float*)d_in[1];
  const float* v = (const float*)d_in[2];
  const float* mask = (const float*)d_in[3];
  float* out = (float*)d_out;

  float* part_kv = (float*)d_ws;                             // 8*64*8192 f32 = 16 MB
  float* part_ks = part_kv + (size_t)CH_ * N_ * D2_ * D_;    // 8*64*128 f32
  u16* kvt = (u16*)(part_ks + (size_t)CH_ * N_ * D2_);       // 64*8192 bf16 = 1 MB
  float* ks = (float*)(kvt + (size_t)N_ * D2_ * D_);         // 64*128 f32

  phase1_mfma<<<dim3(CH_ * N_), dim3(256), 0, stream>>>(k, v, mask, part_kv, part_ks);
  reduce_t<<<dim3(N_ * 8), dim3(256), 0, stream>>>(part_kv, part_ks, kvt, ks);
  phase2_mfma<<<dim3(N_ * 64), dim3(256), 0, stream>>>(q, kvt, ks, out);
}

// Round 4
// 251.511 us; speedup vs baseline: 1.1805x; 1.1805x over previous
//
#include <hip/hip_runtime.h>
#include <hip/hip_bf16.h>
#include <math.h>

// Problem constants
#define B_ 4
#define L_ 4096
#define E_ 1024
#define H_ 16
#define D_ 64
#define N_ 64          // B*H heads
#define D2_ 128        // feature dim 2*D
#define EPS_ 1e-6f

#define CH_ 16             // phase1 L-chunks (1024 blocks)
#define LC_ (L_ / CH_)     // 256 rows per phase1 block
#define LT_ 64             // rows per LDS stage
#define NST_ (LC_ / LT_)   // 4 stages

#define DANG_ 3.83495197e-4f  // 0.5*pi/L

typedef short short8 __attribute__((ext_vector_type(8)));
typedef float f32x4 __attribute__((ext_vector_type(4)));
typedef unsigned int u32;
typedef unsigned short u16;

static __device__ __forceinline__ u32 pack2bf(float a, float b) {
  union { __hip_bfloat16 h; u16 s; } x, y;
  x.h = __float2bfloat16(a);
  y.h = __float2bfloat16(b);
  return (u32)x.s | ((u32)y.s << 16);
}

static __device__ __forceinline__ short bf1(float a) {
  union { __hip_bfloat16 h; short s; } x;
  x.h = __float2bfloat16(a);
  return x.s;
}

// async 16B global -> LDS (wave-uniform LDS base + lane*16)
static __device__ __forceinline__ void gld16(const void* g, void* l) {
  __builtin_amdgcn_global_load_lds(
      (const __attribute__((address_space(1))) unsigned int*)g,
      (__attribute__((address_space(3))) unsigned int*)l, 16, 0, 0);
}

// ---------------------------------------------------------------------------
// Phase 1 (MFMA): partial kv[d][m] = sum_l k_[l][d] * v[l][m], ksum[d]=sum k_
// Register-prefetch pipeline (bounds 256,2 - proven no-spill) + double-
// buffered LDS: ONE barrier per stage. Prefetch for a register buffer is
// issued right after the STAGE that consumes it, giving ~1.5 stages of
// latency cover. CH_=16 -> 1024 blocks for TLP.
// ---------------------------------------------------------------------------
__global__ __launch_bounds__(256, 2) void phase1_mfma(
    const float* __restrict__ k, const float* __restrict__ v,
    const float* __restrict__ mask,
    float* __restrict__ part_kv, float* __restrict__ part_ks) {
  __shared__ __align__(16) u16 ka[2][D2_ * 72];
  __shared__ __align__(16) u16 vt[2][D_ * 72];

  const int bid = blockIdx.x;
  const int n = bid & 63;
  const int ch = bid >> 6;
  const int b = n >> 4;
  const int h = n & 15;
  const int t = threadIdx.x;
  const int wv = t >> 6;
  const int lane = t & 63;
  const int c_lo = lane & 15;
  const int lp = lane >> 4;       // quad
  const int c = wv * 16 + c_lo;   // staging column 0..63

  f32x4 acc[2][4];
#pragma unroll
  for (int i = 0; i < 2; ++i)
#pragma unroll
    for (int j = 0; j < 4; ++j) acc[i][j] = (f32x4)0.f;
  float kss = 0.f, ksc = 0.f;

  const int l0 = ch * LC_;
  const size_t gb0 = (size_t)(b * L_ + l0) * E_ + h * 64 + c;

  // double-buffered prefetch registers (static indexing only)
  float Ak0[8], Ak1[8], Av0[8], Av1[8], Am;
  float Bk0[8], Bk1[8], Bv0[8], Bv1[8], Bm;

#define P1_PREF(Rk0, Rk1, Rv0, Rv1, Rm, S)                                   \
  do {                                                                       \
    const size_t gs_ = gb0 + (size_t)(S) * (LT_ * E_);                       \
    _Pragma("unroll") for (int i_ = 0; i_ < 8; ++i_) {                       \
      const size_t g0_ = gs_ + (size_t)(8 * i_ + 2 * lp) * E_;               \
      Rk0[i_] = k[g0_];                                                      \
      Rk1[i_] = k[g0_ + E_];                                                 \
      Rv0[i_] = v[g0_];                                                      \
      Rv1[i_] = v[g0_ + E_];                                                 \
    }                                                                        \
    Rm = mask[(size_t)b * L_ + l0 + (S) * LT_ + lane];                       \
  } while (0)

#define P1_STAGE(Rk0, Rk1, Rv0, Rv1, Rm, S, BUF)                             \
  do {                                                                       \
    const int lb_ = l0 + (S) * LT_;                                          \
    _Pragma("unroll") for (int i_ = 0; i_ < 8; ++i_) {                       \
      const int l_ = 8 * i_ + 2 * lp;                                        \
      const float m0_ = __shfl(Rm, l_);                                      \
      const float m1_ = __shfl(Rm, l_ + 1);                                  \
      float s0_, c0_, s1_, c1_;                                              \
      __sincosf((float)(lb_ + l_ + 1) * DANG_, &s0_, &c0_);                  \
      __sincosf((float)(lb_ + l_ + 2) * DANG_, &s1_, &c1_);                  \
      const float kr0_ = fmaxf(Rk0[i_], 0.f) * m0_;                          \
      const float kr1_ = fmaxf(Rk1[i_], 0.f) * m1_;                          \
      const float ks0_ = kr0_ * s0_, ks1_ = kr1_ * s1_;                      \
      const float kc0_ = kr0_ * c0_, kc1_ = kr1_ * c1_;                      \
      const int li_ = 4 * i_ + lp;                                           \
      ((u32*)ka[BUF])[c * 36 + li_] = pack2bf(ks0_, ks1_);                   \
      ((u32*)ka[BUF])[(c + 64) * 36 + li_] = pack2bf(kc0_, kc1_);            \
      ((u32*)vt[BUF])[c * 36 + li_] = pack2bf(Rv0[i_] * m0_, Rv1[i_] * m1_); \
      kss += ks0_ + ks1_;                                                    \
      ksc += kc0_ + kc1_;                                                    \
    }                                                                        \
  } while (0)

#define P1_MMA(BUF)                                                          \
  do {                                                                       \
    _Pragma("unroll") for (int kk_ = 0; kk_ < 2; ++kk_) {                    \
      const int colo_ = kk_ * 32 + lp * 8;                                   \
      short8 af_[2], bf_[4];                                                 \
      _Pragma("unroll") for (int dt_ = 0; dt_ < 2; ++dt_)                    \
          af_[dt_] = *(const short8*)                                        \
              &ka[BUF][(wv * 32 + dt_ * 16 + c_lo) * 72 + colo_];            \
      _Pragma("unroll") for (int mt_ = 0; mt_ < 4; ++mt_)                    \
          bf_[mt_] = *(const short8*)                                        \
              &vt[BUF][(mt_ * 16 + c_lo) * 72 + colo_];                      \
      _Pragma("unroll") for (int dt_ = 0; dt_ < 2; ++dt_)                    \
          _Pragma("unroll") for (int mt_ = 0; mt_ < 4; ++mt_)                \
              acc[dt_][mt_] = __builtin_amdgcn_mfma_f32_16x16x32_bf16(       \
                  af_[dt_], bf_[mt_], acc[dt_][mt_], 0, 0, 0);               \
    }                                                                        \
  } while (0)

  // prologue: stage 0 into buf0; refill A for stage 2; prefetch B stage 1
  P1_PREF(Ak0, Ak1, Av0, Av1, Am, 0);
  P1_STAGE(Ak0, Ak1, Av0, Av1, Am, 0, 0);
  if (2 < NST_) P1_PREF(Ak0, Ak1, Av0, Av1, Am, 2);
  P1_PREF(Bk0, Bk1, Bv0, Bv1, Bm, 1);
  __syncthreads();

#pragma unroll
  for (int st = 0; st < NST_; st += 2) {
    // even half: stage st+1 into buf1 (B regs), refill B; MFMA buf0 (= st)
    if (st + 1 < NST_) {
      P1_STAGE(Bk0, Bk1, Bv0, Bv1, Bm, st + 1, 1);
      if (st + 3 < NST_) P1_PREF(Bk0, Bk1, Bv0, Bv1, Bm, st + 3);
    }
    P1_MMA(0);
    __syncthreads();
    // odd half: stage st+2 into buf0 (A regs), refill A; MFMA buf1 (= st+1)
    if (st + 1 < NST_) {
      if (st + 2 < NST_) {
        P1_STAGE(Ak0, Ak1, Av0, Av1, Am, st + 2, 0);
        if (st + 4 < NST_) P1_PREF(Ak0, Ak1, Av0, Av1, Am, st + 4);
      }
      P1_MMA(1);
      __syncthreads();
    }
  }

  // write partial kv (fp32). C layout: row(d)=quad*4+r, col(m)=lane&15
  const size_t pbase = (size_t)(ch * N_ + n) * (D2_ * D_);
#pragma unroll
  for (int dt = 0; dt < 2; ++dt) {
    const int d = wv * 32 + dt * 16 + lp * 4;
#pragma unroll
    for (int mt = 0; mt < 4; ++mt) {
      const int mcol = mt * 16 + c_lo;
#pragma unroll
      for (int r = 0; r < 4; ++r)
        part_kv[pbase + (size_t)(d + r) * D_ + mcol] = acc[dt][mt][r];
    }
  }
  // ksum partials: reduce over lp groups (lanes +-16, +-32)
  kss += __shfl_xor(kss, 16); kss += __shfl_xor(kss, 32);
  ksc += __shfl_xor(ksc, 16); ksc += __shfl_xor(ksc, 32);
  if (lp == 0) {
    part_ks[(size_t)(ch * N_ + n) * D2_ + c] = kss;
    part_ks[(size_t)(ch * N_ + n) * D2_ + c + 64] = ksc;
  }
}

// ---------------------------------------------------------------------------
// Reduce: sum chunk partials; emit kvT[n][m][d] bf16 + ksum fp32.
// 512 blocks (8 e-slices per head), f32x4 loads, small LDS transpose.
// ---------------------------------------------------------------------------
__global__ __launch_bounds__(256) void reduce_t(
    const float* __restrict__ part_kv, const float* __restrict__ part_ks,
    u16* __restrict__ kvt, float* __restrict__ ks) {
  __shared__ __align__(16) float tsh[16 * 68];
  const int bid = blockIdx.x;
  const int n = bid >> 3;
  const int sl = bid & 7;
  const int t = threadIdx.x;

  const int e0 = sl * 1024 + t * 4;  // covers d=sl*16..+16, m=0..63
  f32x4 s = (f32x4)0.f;
#pragma unroll
  for (int cc = 0; cc < CH_; ++cc)
    s += *(const f32x4*)&part_kv[(size_t)(cc * N_ + n) * (D2_ * D_) + e0];
  *(f32x4*)&tsh[(t >> 4) * 68 + (t & 15) * 4] = s;

  if (sl == 0 && t < D2_) {
    float ss = 0.f;
#pragma unroll
    for (int cc = 0; cc < CH_; ++cc)
      ss += part_ks[(size_t)(cc * N_ + n) * D2_ + t];
    ks[n * D2_ + t] = ss;
  }
  __syncthreads();

  // transpose out: thread -> m = t>>2, 4 consecutive d
  const int m = t >> 2;
  const int d4 = (t & 3) * 4;
  const u32 lo = pack2bf(tsh[(d4 + 0) * 68 + m], tsh[(d4 + 1) * 68 + m]);
  const u32 hi = pack2bf(tsh[(d4 + 2) * 68 + m], tsh[(d4 + 3) * 68 + m]);
  uint2 pk; pk.x = lo; pk.y = hi;
  *(uint2*)&kvt[(size_t)n * (D2_ * D_) + (size_t)m * D2_ + sl * 16 + d4] = pk;
}

// ---------------------------------------------------------------------------
// Phase 2 (MFMA): out[l][m] = z[l] * sum_d q_[l][d] * kv[d][m]
// Two 64-row l-chunks per block; kvt staged ONCE per block. All staging via
// global_load_lds width=16 (12 insts/wave), one barrier per block. Granules
// XOR-swizzled on the GLOBAL source and on the LDS reads (both-sides rule).
// z via 5th B-fragment whose column 0 is ksum.
// ---------------------------------------------------------------------------
__global__ __launch_bounds__(256, 3) void phase2_mfma(
    const float* __restrict__ q, const u16* __restrict__ kvt,
    const float* __restrict__ ks, float* __restrict__ out) {
  __shared__ __align__(16) float qsh[2 * 64 * 64];  // 32KB raw q, 2 chunks
  __shared__ __align__(16) u16 kbsh[64 * 128];      // 16KB kvt rows

  const int bid = blockIdx.x;
  const int n = bid & 63;
  const int g2 = bid >> 6;          // 0..31
  const int b = n >> 4, h = n & 15;
  const int t = threadIdx.x;
  const int wv = t >> 6, lane = t & 63;
  const int c_lo = lane & 15, quad = lane >> 4;
  const int l0 = g2 * 128;

  // ---- async staging: wave wv owns rows [wv*16, wv*16+16) of each tile ----
  const float* qbase = q + (size_t)(b * L_ + l0) * E_ + h * 64;
  const u16* kvbase = kvt + (size_t)n * (D2_ * D_);
  const int rsub = lane >> 4;  // row within one 1KB instruction
  const int g = lane & 15;     // physical 16B granule within row
#pragma unroll
  for (int j = 0; j < 4; ++j) {
    const int r = wv * 16 + j * 4 + rsub;
    const int sw = (g ^ (r & 15));
    gld16(kvbase + (size_t)r * D2_ + (sw << 3),
          kbsh + (wv * 16 + j * 4) * 128);
    gld16(qbase + (size_t)r * E_ + (sw << 2),
          qsh + (wv * 16 + j * 4) * 64);
    gld16(qbase + (size_t)(64 + r) * E_ + (sw << 2),
          qsh + 4096 + (wv * 16 + j * 4) * 64);
  }

  // ---- ksum B-fragments (register path, col 0 = ksum) ----
  const float* ksn = ks + n * D2_;
  short8 bks[4];
#pragma unroll
  for (int kk = 0; kk < 4; ++kk) {
    const f32x4 ka_ = *(const f32x4*)(ksn + kk * 32 + quad * 8);
    const f32x4 kb_ = *(const f32x4*)(ksn + kk * 32 + quad * 8 + 4);
    short8 tt = {0, 0, 0, 0, 0, 0, 0, 0};
    if (c_lo == 0) {
#pragma unroll
      for (int j = 0; j < 4; ++j) {
        tt[j] = bf1(ka_[j]);
        tt[j + 4] = bf1(kb_[j]);
      }
    }
    bks[kk] = tt;
  }

  __syncthreads();  // drains vmcnt(0): all global_load_lds landed

#pragma unroll
  for (int cc = 0; cc < 2; ++cc) {
    const int row = wv * 16 + c_lo;  // A-row within chunk
    const int glr = l0 + cc * 64 + row;
    float sv, cv;
    __sincosf((float)(glr + 1) * DANG_, &sv, &cv);

    // A-fragments from raw q LDS (swizzled reads)
    const float* qrow = qsh + cc * 4096 + row * 64;
    const int sw = row & 15;
    const f32x4 a0 = *(const f32x4*)(qrow + (((2 * quad) ^ sw) << 2));
    const f32x4 a1 = *(const f32x4*)(qrow + (((2 * quad + 1) ^ sw) << 2));
    const f32x4 a2 = *(const f32x4*)(qrow + (((8 + 2 * quad) ^ sw) << 2));
    const f32x4 a3 = *(const f32x4*)(qrow + (((9 + 2 * quad) ^ sw) << 2));

    short8 af[4];
#pragma unroll
    for (int j = 0; j < 4; ++j) {
      const float x0 = fmaxf(a0[j], 0.f);
      const float x1 = fmaxf(a1[j], 0.f);
      const float x2 = fmaxf(a2[j], 0.f);
      const float x3 = fmaxf(a3[j], 0.f);
      af[0][j] = bf1(x0 * sv); af[0][j + 4] = bf1(x1 * sv);
      af[1][j] = bf1(x2 * sv); af[1][j + 4] = bf1(x3 * sv);
      af[2][j] = bf1(x0 * cv); af[2][j + 4] = bf1(x1 * cv);
      af[3][j] = bf1(x2 * cv); af[3][j + 4] = bf1(x3 * cv);
    }

    f32x4 acc[4];
#pragma unroll
    for (int mt = 0; mt < 4; ++mt) acc[mt] = (f32x4)0.f;
    f32x4 acc5 = (f32x4)0.f;

#pragma unroll
    for (int kk = 0; kk < 4; ++kk) {
#pragma unroll
      for (int mt = 0; mt < 4; ++mt) {
        const int m = mt * 16 + c_lo;
        const short8 bfr = *(const short8*)
            &kbsh[m * 128 + (((kk * 4 + quad) ^ (m & 15)) << 3)];
        acc[mt] =
            __builtin_amdgcn_mfma_f32_16x16x32_bf16(af[kk], bfr, acc[mt], 0, 0, 0);
      }
      acc5 = __builtin_amdgcn_mfma_f32_16x16x32_bf16(af[kk], bks[kk], acc5, 0, 0, 0);
    }

    // epilogue: z from acc5 col 0 (lane quad*16), scale, store
#pragma unroll
    for (int r = 0; r < 4; ++r) {
      const float den = __shfl(acc5[r], quad * 16);
      const float z = 1.f / fmaxf(den, EPS_);
      const int gl = l0 + cc * 64 + wv * 16 + quad * 4 + r;
      const size_t ob = (size_t)n * (L_ * D_) + (size_t)gl * D_;
#pragma unroll
      for (int mt = 0; mt < 4; ++mt)
        out[ob + mt * 16 + c_lo] = acc[mt][r] * z;
    }
  }
}

// ---------------------------------------------------------------------------
extern "C" void kernel_launch(void* const* d_in, const int* in_sizes, int n_in,
                              void* d_out, int out_size, void* d_ws,
                              size_t ws_size, hipStream_t stream) {
  const float* q = (const float*)d_in[0];
  const float* k = (const float*)d_in[1];
  const float* v = (const float*)d_in[2];
  const float* mask = (const float*)d_in[3];
  float* out = (float*)d_out;

  float* part_kv = (float*)d_ws;                             // 16*64*8192 f32 = 33.5 MB
  float* part_ks = part_kv + (size_t)CH_ * N_ * D2_ * D_;    // 16*64*128 f32
  u16* kvt = (u16*)(part_ks + (size_t)CH_ * N_ * D2_);       // 64*8192 bf16 = 1 MB
  float* ks = (float*)(kvt + (size_t)N_ * D2_ * D_);         // 64*128 f32

  phase1_mfma<<<dim3(CH_ * N_), dim3(256), 0, stream>>>(k, v, mask, part_kv, part_ks);
  reduce_t<<<dim3(N_ * 8), dim3(256), 0, stream>>>(part_kv, part_ks, kvt, ks);
  phase2_mfma<<<dim3(N_ * 32), dim3(256), 0, stream>>>(q, kvt, ks, out);
}

// Round 5
// 247.024 us; speedup vs baseline: 1.2020x; 1.0182x over previous
//
#include <hip/hip_runtime.h>
#include <hip/hip_bf16.h>
#include <math.h>

// Problem constants
#define B_ 4
#define L_ 4096
#define E_ 1024
#define H_ 16
#define D_ 64
#define N_ 64          // B*H heads
#define D2_ 128        // feature dim 2*D
#define EPS_ 1e-6f

#define CH_ 16             // phase1 L-chunks (1024 blocks)
#define LC_ (L_ / CH_)     // 256 rows per phase1 block
#define LT2_ 32            // rows per phase1 stage
#define NST_ (LC_ / LT2_)  // 8 stages

#define DANG_ 3.83495197e-4f  // 0.5*pi/L

typedef short short8 __attribute__((ext_vector_type(8)));
typedef float f32x4 __attribute__((ext_vector_type(4)));
typedef unsigned int u32;
typedef unsigned short u16;

static __device__ __forceinline__ u32 pack2bf(float a, float b) {
  union { __hip_bfloat16 h; u16 s; } x, y;
  x.h = __float2bfloat16(a);
  y.h = __float2bfloat16(b);
  return (u32)x.s | ((u32)y.s << 16);
}

static __device__ __forceinline__ short bf1(float a) {
  union { __hip_bfloat16 h; short s; } x;
  x.h = __float2bfloat16(a);
  return x.s;
}

// async 16B global -> LDS (wave-uniform LDS base + lane*16)
static __device__ __forceinline__ void gld16(const void* g, void* l) {
  __builtin_amdgcn_global_load_lds(
      (const __attribute__((address_space(1))) unsigned int*)g,
      (__attribute__((address_space(3))) unsigned int*)l, 16, 0, 0);
}

#define BAR_() __builtin_amdgcn_s_barrier()
#define WAIT_LGKM0_()                                     \
  {                                                       \
    asm volatile("s_waitcnt lgkmcnt(0)" ::: "memory");    \
    __builtin_amdgcn_sched_barrier(0);                    \
  }
#define WAIT_VM4_()                                       \
  {                                                       \
    asm volatile("s_waitcnt vmcnt(4)" ::: "memory");      \
    __builtin_amdgcn_sched_barrier(0);                    \
  }
#define WAIT_VM0_()                                       \
  {                                                       \
    asm volatile("s_waitcnt vmcnt(0)" ::: "memory");      \
    __builtin_amdgcn_sched_barrier(0);                    \
  }

// ---------------------------------------------------------------------------
// Phase 1 (MFMA): partial kv[d][m] = sum_l k_[l][d] * v[l][m], ksum[d]=sum k_
// ALL staging via global_load_lds (zero staging VGPRs, regalloc-proof).
// Per 32-row stage: 4 gld16/wave into double-buffered raw f32 LDS (XOR-
// swizzled global source, both-sides rule); pack pass (relu*mask*sin/cos ->
// bf16 transposed tiles); MFMA K=32. Counted vmcnt(4) + raw s_barrier keep
// the st+2 prefetch in flight across barriers (never drained in-loop).
// ksum via a 5th ones-column B-fragment (col 0 = 1).
// ---------------------------------------------------------------------------
__global__ __launch_bounds__(256, 3) void phase1_mfma(
    const float* __restrict__ k, const float* __restrict__ v,
    const float* __restrict__ mask,
    float* __restrict__ part_kv, float* __restrict__ part_ks) {
  __shared__ __align__(16) float kraw[2][LT2_ * 64];  // 2 x 8 KB
  __shared__ __align__(16) float vraw[2][LT2_ * 64];  // 2 x 8 KB
  __shared__ __align__(16) u16 ka[D2_ * 40];          // 10 KB (pad 40)
  __shared__ __align__(16) u16 vt[D_ * 40];           // 5 KB
  __shared__ float msh[LC_];                          // 1 KB

  const int bid = blockIdx.x;
  const int n = bid & 63;
  const int ch = bid >> 6;
  const int b = n >> 4;
  const int h = n & 15;
  const int t = threadIdx.x;
  const int wv = t >> 6;
  const int lane = t & 63;
  const int c_lo = lane & 15;     // frag row / granule index
  const int lp = lane >> 4;       // quad
  const int lp2 = t >> 4;         // pack: l-pair 0..15
  const int dg = t & 15;          // pack: d-group 0..15
  const int l0 = ch * LC_;

  u32* ka32 = (u32*)ka;
  u32* vt32 = (u32*)vt;

  f32x4 acc[2][4];
#pragma unroll
  for (int i = 0; i < 2; ++i)
#pragma unroll
    for (int j = 0; j < 4; ++j) acc[i][j] = (f32x4)0.f;
  f32x4 acc5[2];
  acc5[0] = (f32x4)0.f;
  acc5[1] = (f32x4)0.f;

  // ones B-fragment: column m=0 all-ones, others zero
  short8 bones = {0, 0, 0, 0, 0, 0, 0, 0};
  if (c_lo == 0) {
#pragma unroll
    for (int j = 0; j < 8; ++j) bones[j] = (short)0x3F80;
  }

// issue one stage's raw k,v (4 gld16/wave). rows r32 = 8*wv + 4*j + lp,
// global source granule XOR-swizzled by (r32 & 15).
#define P1_GLD(S, BUF)                                                       \
  do {                                                                       \
    _Pragma("unroll") for (int j_ = 0; j_ < 2; ++j_) {                       \
      const int r32_ = 8 * wv + 4 * j_ + lp;                                 \
      const int lg_ = l0 + (S) * LT2_ + r32_;                                \
      const size_t gs_ = (size_t)(b * L_ + lg_) * E_ + h * 64;               \
      const int so_ = (c_lo ^ (r32_ & 15)) << 2;                             \
      gld16(k + gs_ + so_, &kraw[BUF][(8 * wv + 4 * j_) * 64]);              \
      gld16(v + gs_ + so_, &vraw[BUF][(8 * wv + 4 * j_) * 64]);              \
    }                                                                        \
  } while (0)

// pack: thread (lp2,dg) handles l32 = 2*lp2, 2*lp2+1 and d = dg + 16*{0..3}
#define P1_PACK(BUF, S)                                                      \
  do {                                                                       \
    const int la_ = 2 * lp2, lb_ = la_ + 1;                                  \
    const float m0_ = msh[(S) * LT2_ + la_];                                 \
    const float m1_ = msh[(S) * LT2_ + lb_];                                 \
    const int lga_ = l0 + (S) * LT2_ + la_;                                  \
    float s0_, c0_, s1_, c1_;                                                \
    __sincosf((float)(lga_ + 1) * DANG_, &s0_, &c0_);                        \
    __sincosf((float)(lga_ + 2) * DANG_, &s1_, &c1_);                        \
    const int sa_ = la_ & 15, sb_ = lb_ & 15;                                \
    _Pragma("unroll") for (int dj_ = 0; dj_ < 4; ++dj_) {                    \
      const int d_ = dg + 16 * dj_;                                          \
      const int gl_ = d_ >> 2, su_ = d_ & 3;                                 \
      const float k0_ = kraw[BUF][la_ * 64 + ((gl_ ^ sa_) << 2) + su_];      \
      const float k1_ = kraw[BUF][lb_ * 64 + ((gl_ ^ sb_) << 2) + su_];      \
      const float v0_ = vraw[BUF][la_ * 64 + ((gl_ ^ sa_) << 2) + su_];      \
      const float v1_ = vraw[BUF][lb_ * 64 + ((gl_ ^ sb_) << 2) + su_];      \
      const float kr0_ = fmaxf(k0_, 0.f) * m0_;                              \
      const float kr1_ = fmaxf(k1_, 0.f) * m1_;                              \
      ka32[d_ * 20 + lp2] = pack2bf(kr0_ * s0_, kr1_ * s1_);                 \
      ka32[(d_ + 64) * 20 + lp2] = pack2bf(kr0_ * c0_, kr1_ * c1_);          \
      vt32[d_ * 20 + lp2] = pack2bf(v0_ * m0_, v1_ * m1_);                   \
    }                                                                        \
  } while (0)

// MFMA one K=32 step: 8 real + 2 ones MFMAs
#define P1_MMA()                                                             \
  do {                                                                       \
    short8 af_[2], bf_[4];                                                   \
    _Pragma("unroll") for (int dt_ = 0; dt_ < 2; ++dt_)                      \
        af_[dt_] = *(const short8*)&ka[(wv * 32 + dt_ * 16 + c_lo) * 40 +    \
                                       lp * 8];                              \
    _Pragma("unroll") for (int mt_ = 0; mt_ < 4; ++mt_)                      \
        bf_[mt_] = *(const short8*)&vt[(mt_ * 16 + c_lo) * 40 + lp * 8];     \
    _Pragma("unroll") for (int dt_ = 0; dt_ < 2; ++dt_) {                    \
      _Pragma("unroll") for (int mt_ = 0; mt_ < 4; ++mt_)                    \
          acc[dt_][mt_] = __builtin_amdgcn_mfma_f32_16x16x32_bf16(           \
              af_[dt_], bf_[mt_], acc[dt_][mt_], 0, 0, 0);                   \
      acc5[dt_] = __builtin_amdgcn_mfma_f32_16x16x32_bf16(af_[dt_], bones,   \
                                                          acc5[dt_], 0, 0,   \
                                                          0);                \
    }                                                                        \
  } while (0)

// one steady-state stage: pack, tile-barrier, mfma, prefetch st+2, vm-wait
#define P1_STEP(S, BUF)                                                      \
  do {                                                                       \
    P1_PACK(BUF, S);                                                         \
    WAIT_LGKM0_();                                                           \
    BAR_();                                                                  \
    P1_MMA();                                                                \
    P1_GLD((S) + 2, BUF);                                                    \
    WAIT_VM4_();                                                             \
    BAR_();                                                                  \
  } while (0)

  // prologue: mask (wave0) + stages 0,1
  if (wv == 0) gld16(mask + (size_t)b * L_ + l0 + lane * 4, msh);
  P1_GLD(0, 0);
  P1_GLD(1, 1);
  WAIT_VM4_();  // mask + stage0 landed (stage1's 4 remain in flight)
  BAR_();

  P1_STEP(0, 0);
  P1_STEP(1, 1);
  P1_STEP(2, 0);
  P1_STEP(3, 1);
  P1_STEP(4, 0);
  P1_STEP(5, 1);
  // stage 6: no prefetch left; drain stage 7 fully
  P1_PACK(0, 6);
  WAIT_LGKM0_();
  BAR_();
  P1_MMA();
  WAIT_VM0_();
  BAR_();
  // stage 7: last
  P1_PACK(1, 7);
  WAIT_LGKM0_();
  BAR_();
  P1_MMA();

  // write partial kv (fp32). C layout: row(d)=quad*4+r, col(m)=lane&15
  const size_t pbase = (size_t)(ch * N_ + n) * (D2_ * D_);
#pragma unroll
  for (int dt = 0; dt < 2; ++dt) {
    const int d = wv * 32 + dt * 16 + lp * 4;
#pragma unroll
    for (int mt = 0; mt < 4; ++mt) {
      const int mcol = mt * 16 + c_lo;
#pragma unroll
      for (int r = 0; r < 4; ++r)
        part_kv[pbase + (size_t)(d + r) * D_ + mcol] = acc[dt][mt][r];
    }
  }
  // ksum from ones-MFMA accumulator: column 0 lives in lanes with c_lo==0
  if (c_lo == 0) {
#pragma unroll
    for (int dt = 0; dt < 2; ++dt)
#pragma unroll
      for (int r = 0; r < 4; ++r)
        part_ks[(size_t)(ch * N_ + n) * D2_ + wv * 32 + dt * 16 + lp * 4 + r] =
            acc5[dt][r];
  }
}

// ---------------------------------------------------------------------------
// Reduce: sum chunk partials; emit kvT[n][m][d] bf16 + ksum fp32.
// 512 blocks (8 e-slices per head), f32x4 loads, small LDS transpose.
// ---------------------------------------------------------------------------
__global__ __launch_bounds__(256) void reduce_t(
    const float* __restrict__ part_kv, const float* __restrict__ part_ks,
    u16* __restrict__ kvt, float* __restrict__ ks) {
  __shared__ __align__(16) float tsh[16 * 68];
  const int bid = blockIdx.x;
  const int n = bid >> 3;
  const int sl = bid & 7;
  const int t = threadIdx.x;

  const int e0 = sl * 1024 + t * 4;  // covers d=sl*16..+16, m=0..63
  f32x4 s = (f32x4)0.f;
#pragma unroll
  for (int cc = 0; cc < CH_; ++cc)
    s += *(const f32x4*)&part_kv[(size_t)(cc * N_ + n) * (D2_ * D_) + e0];
  *(f32x4*)&tsh[(t >> 4) * 68 + (t & 15) * 4] = s;

  if (sl == 0 && t < D2_) {
    float ss = 0.f;
#pragma unroll
    for (int cc = 0; cc < CH_; ++cc)
      ss += part_ks[(size_t)(cc * N_ + n) * D2_ + t];
    ks[n * D2_ + t] = ss;
  }
  __syncthreads();

  // transpose out: thread -> m = t>>2, 4 consecutive d
  const int m = t >> 2;
  const int d4 = (t & 3) * 4;
  const u32 lo = pack2bf(tsh[(d4 + 0) * 68 + m], tsh[(d4 + 1) * 68 + m]);
  const u32 hi = pack2bf(tsh[(d4 + 2) * 68 + m], tsh[(d4 + 3) * 68 + m]);
  uint2 pk; pk.x = lo; pk.y = hi;
  *(uint2*)&kvt[(size_t)n * (D2_ * D_) + (size_t)m * D2_ + sl * 16 + d4] = pk;
}

// ---------------------------------------------------------------------------
// Phase 2 (MFMA): out[l][m] = z[l] * sum_d q_[l][d] * kv[d][m]
// Two 64-row l-chunks per block; kvt staged ONCE per block. All staging via
// global_load_lds width=16 (12 insts/wave), one barrier per block. Granules
// XOR-swizzled on the GLOBAL source and on the LDS reads (both-sides rule).
// z via 5th B-fragment whose column 0 is ksum.
// ---------------------------------------------------------------------------
__global__ __launch_bounds__(256, 3) void phase2_mfma(
    const float* __restrict__ q, const u16* __restrict__ kvt,
    const float* __restrict__ ks, float* __restrict__ out) {
  __shared__ __align__(16) float qsh[2 * 64 * 64];  // 32KB raw q, 2 chunks
  __shared__ __align__(16) u16 kbsh[64 * 128];      // 16KB kvt rows

  const int bid = blockIdx.x;
  const int n = bid & 63;
  const int g2 = bid >> 6;          // 0..31
  const int b = n >> 4, h = n & 15;
  const int t = threadIdx.x;
  const int wv = t >> 6, lane = t & 63;
  const int c_lo = lane & 15, quad = lane >> 4;
  const int l0 = g2 * 128;

  // ---- async staging: wave wv owns rows [wv*16, wv*16+16) of each tile ----
  const float* qbase = q + (size_t)(b * L_ + l0) * E_ + h * 64;
  const u16* kvbase = kvt + (size_t)n * (D2_ * D_);
  const int rsub = lane >> 4;  // row within one 1KB instruction
  const int g = lane & 15;     // physical 16B granule within row
#pragma unroll
  for (int j = 0; j < 4; ++j) {
    const int r = wv * 16 + j * 4 + rsub;
    const int sw = (g ^ (r & 15));
    gld16(kvbase + (size_t)r * D2_ + (sw << 3),
          kbsh + (wv * 16 + j * 4) * 128);
    gld16(qbase + (size_t)r * E_ + (sw << 2),
          qsh + (wv * 16 + j * 4) * 64);
    gld16(qbase + (size_t)(64 + r) * E_ + (sw << 2),
          qsh + 4096 + (wv * 16 + j * 4) * 64);
  }

  // ---- ksum B-fragments (register path, col 0 = ksum) ----
  const float* ksn = ks + n * D2_;
  short8 bks[4];
#pragma unroll
  for (int kk = 0; kk < 4; ++kk) {
    const f32x4 ka_ = *(const f32x4*)(ksn + kk * 32 + quad * 8);
    const f32x4 kb_ = *(const f32x4*)(ksn + kk * 32 + quad * 8 + 4);
    short8 tt = {0, 0, 0, 0, 0, 0, 0, 0};
    if (c_lo == 0) {
#pragma unroll
      for (int j = 0; j < 4; ++j) {
        tt[j] = bf1(ka_[j]);
        tt[j + 4] = bf1(kb_[j]);
      }
    }
    bks[kk] = tt;
  }

  __syncthreads();  // drains vmcnt(0): all global_load_lds landed

#pragma unroll
  for (int cc = 0; cc < 2; ++cc) {
    const int row = wv * 16 + c_lo;  // A-row within chunk
    const int glr = l0 + cc * 64 + row;
    float sv, cv;
    __sincosf((float)(glr + 1) * DANG_, &sv, &cv);

    // A-fragments from raw q LDS (swizzled reads)
    const float* qrow = qsh + cc * 4096 + row * 64;
    const int sw = row & 15;
    const f32x4 a0 = *(const f32x4*)(qrow + (((2 * quad) ^ sw) << 2));
    const f32x4 a1 = *(const f32x4*)(qrow + (((2 * quad + 1) ^ sw) << 2));
    const f32x4 a2 = *(const f32x4*)(qrow + (((8 + 2 * quad) ^ sw) << 2));
    const f32x4 a3 = *(const f32x4*)(qrow + (((9 + 2 * quad) ^ sw) << 2));

    short8 af[4];
#pragma unroll
    for (int j = 0; j < 4; ++j) {
      const float x0 = fmaxf(a0[j], 0.f);
      const float x1 = fmaxf(a1[j], 0.f);
      const float x2 = fmaxf(a2[j], 0.f);
      const float x3 = fmaxf(a3[j], 0.f);
      af[0][j] = bf1(x0 * sv); af[0][j + 4] = bf1(x1 * sv);
      af[1][j] = bf1(x2 * sv); af[1][j + 4] = bf1(x3 * sv);
      af[2][j] = bf1(x0 * cv); af[2][j + 4] = bf1(x1 * cv);
      af[3][j] = bf1(x2 * cv); af[3][j + 4] = bf1(x3 * cv);
    }

    f32x4 acc[4];
#pragma unroll
    for (int mt = 0; mt < 4; ++mt) acc[mt] = (f32x4)0.f;
    f32x4 acc5 = (f32x4)0.f;

#pragma unroll
    for (int kk = 0; kk < 4; ++kk) {
#pragma unroll
      for (int mt = 0; mt < 4; ++mt) {
        const int m = mt * 16 + c_lo;
        const short8 bfr = *(const short8*)
            &kbsh[m * 128 + (((kk * 4 + quad) ^ (m & 15)) << 3)];
        acc[mt] =
            __builtin_amdgcn_mfma_f32_16x16x32_bf16(af[kk], bfr, acc[mt], 0, 0, 0);
      }
      acc5 = __builtin_amdgcn_mfma_f32_16x16x32_bf16(af[kk], bks[kk], acc5, 0, 0, 0);
    }

    // epilogue: z from acc5 col 0 (lane quad*16), scale, store
#pragma unroll
    for (int r = 0; r < 4; ++r) {
      const float den = __shfl(acc5[r], quad * 16);
      const float z = 1.f / fmaxf(den, EPS_);
      const int gl = l0 + cc * 64 + wv * 16 + quad * 4 + r;
      const size_t ob = (size_t)n * (L_ * D_) + (size_t)gl * D_;
#pragma unroll
      for (int mt = 0; mt < 4; ++mt)
        out[ob + mt * 16 + c_lo] = acc[mt][r] * z;
    }
  }
}

// ---------------------------------------------------------------------------
extern "C" void kernel_launch(void* const* d_in, const int* in_sizes, int n_in,
                              void* d_out, int out_size, void* d_ws,
                              size_t ws_size, hipStream_t stream) {
  const float* q = (const float*)d_in[0];
  const float* k = (const float*)d_in[1];
  const float* v = (const float*)d_in[2];
  const float* mask = (const float*)d_in[3];
  float* out = (float*)d_out;

  float* part_kv = (float*)d_ws;                             // 16*64*8192 f32 = 33.5 MB
  float* part_ks = part_kv + (size_t)CH_ * N_ * D2_ * D_;    // 16*64*128 f32
  u16* kvt = (u16*)(part_ks + (size_t)CH_ * N_ * D2_);       // 64*8192 bf16 = 1 MB
  float* ks = (float*)(kvt + (size_t)N_ * D2_ * D_);         // 64*128 f32

  phase1_mfma<<<dim3(CH_ * N_), dim3(256), 0, stream>>>(k, v, mask, part_kv, part_ks);
  reduce_t<<<dim3(N_ * 8), dim3(256), 0, stream>>>(part_kv, part_ks, kvt, ks);
  phase2_mfma<<<dim3(N_ * 32), dim3(256), 0, stream>>>(q, kvt, ks, out);
}

// Round 6
// 238.927 us; speedup vs baseline: 1.2427x; 1.0339x over previous
//
#include <hip/hip_runtime.h>
#include <hip/hip_bf16.h>
#include <math.h>

// Problem constants
#define B_ 4
#define L_ 4096
#define E_ 1024
#define H_ 16
#define D_ 64
#define N_ 64          // B*H heads
#define D2_ 128        // feature dim 2*D
#define EPS_ 1e-6f

#define CH_ 16             // phase1 L-chunks
#define LC_ (L_ / CH_)     // 256 rows per phase1 block
#define ST_ 16             // rows per phase1 stage
#define NSTG_ 16           // stages per block

#define DANG_ 3.83495197e-4f  // 0.5*pi/L

typedef short short8 __attribute__((ext_vector_type(8)));
typedef float f32x4 __attribute__((ext_vector_type(4)));
typedef unsigned int u32;
typedef unsigned short u16;

static __device__ __forceinline__ u32 pack2bf(float a, float b) {
  union { __hip_bfloat16 h; u16 s; } x, y;
  x.h = __float2bfloat16(a);
  y.h = __float2bfloat16(b);
  return (u32)x.s | ((u32)y.s << 16);
}

static __device__ __forceinline__ short bf1(float a) {
  union { __hip_bfloat16 h; short s; } x;
  x.h = __float2bfloat16(a);
  return x.s;
}

// async 16B global -> LDS (wave-uniform LDS base + lane*16)
static __device__ __forceinline__ void gld16(const void* g, void* l) {
  __builtin_amdgcn_global_load_lds(
      (const __attribute__((address_space(1))) unsigned int*)g,
      (__attribute__((address_space(3))) unsigned int*)l, 16, 0, 0);
}

#define BAR_() __builtin_amdgcn_s_barrier()
#define WAIT_LGKM0_()                                     \
  {                                                       \
    asm volatile("s_waitcnt lgkmcnt(0)" ::: "memory");    \
    __builtin_amdgcn_sched_barrier(0);                    \
  }
#define WAIT_VM4_()                                       \
  {                                                       \
    asm volatile("s_waitcnt vmcnt(4)" ::: "memory");      \
    __builtin_amdgcn_sched_barrier(0);                    \
  }
#define WAIT_VM0_()                                       \
  {                                                       \
    asm volatile("s_waitcnt vmcnt(0)" ::: "memory");      \
    __builtin_amdgcn_sched_barrier(0);                    \
  }

// ---------------------------------------------------------------------------
// Phase 1 (MFMA): partial kv[d][m] = sum_l k_[l][d] * v[l][m], ksum[d]=sum k_
// HEAD-PAIR blocks: each block reads 512B-contiguous row segments (2 heads)
// instead of 256B -- tests/exploits the DRAM granule-at-4KB-stride theory.
// 512 blocks (2/CU exact). 16-row stages, TRIPLE-buffered raw f32 LDS via
// global_load_lds (XOR-swizzled global source, both-sides rule). Per 2-stage
// group: pack both halves of K=32 tiles for both heads, 2 barriers, 20 MFMA,
// counted vmcnt(4) (loads retire in order -> next group's two stages are
// provably landed). ksum via ones-column B-fragment.
// ---------------------------------------------------------------------------
__global__ __launch_bounds__(256, 2) void phase1_mfma(
    const float* __restrict__ k, const float* __restrict__ v,
    const float* __restrict__ mask,
    float* __restrict__ part_kv, float* __restrict__ part_ks) {
  __shared__ __align__(16) float kraw[3][ST_ * 128];  // 3 x 8 KB
  __shared__ __align__(16) float vraw[3][ST_ * 128];  // 3 x 8 KB
  __shared__ __align__(16) u16 ka[2][D2_ * 36];       // 2 x 9 KB
  __shared__ __align__(16) u16 vt[2][D_ * 36];        // 2 x 4.5 KB
  __shared__ float msh[LC_];                          // 1 KB

  const int bid = blockIdx.x;
  const int p = bid & 31;         // head pair 0..31
  const int ch = bid >> 5;        // 0..15
  const int b = p >> 3;
  const int hcol0 = (p & 7) * 128;  // f32 col of pair segment within E
  const int t = threadIdx.x;
  const int wv = t >> 6;
  const int lane = t & 63;
  const int c_lo = lane & 15;     // frag row
  const int lp = lane >> 4;       // k-octet
  const int l0 = ch * LC_;

  // pack-thread mapping
  const int hh = t >> 7;          // head within pair (0/1)
  const int tt = t & 127;
  const int lp2h = tt >> 4;       // row-pair within stage 0..7
  const int dg = tt & 15;         // d-group 0..15

  u32* ka32 = (u32*)ka;
  u32* vt32 = (u32*)vt;

  f32x4 acc[2][2][4];             // [head][dt][mt]
#pragma unroll
  for (int hq = 0; hq < 2; ++hq)
#pragma unroll
    for (int i = 0; i < 2; ++i)
#pragma unroll
      for (int j = 0; j < 4; ++j) acc[hq][i][j] = (f32x4)0.f;
  f32x4 acc5[2][2];               // [head][dt] ksum
#pragma unroll
  for (int hq = 0; hq < 2; ++hq) {
    acc5[hq][0] = (f32x4)0.f;
    acc5[hq][1] = (f32x4)0.f;
  }

  // ones B-fragment: column m=0 all-ones
  short8 bones = {0, 0, 0, 0, 0, 0, 0, 0};
  if (c_lo == 0) {
#pragma unroll
    for (int j = 0; j < 8; ++j) bones[j] = (short)0x3F80;
  }

// issue one 16-row stage of raw k,v (4 gld16/wave = 4 KB/wave).
// wave wv owns rows {4wv..4wv+3}; each gld16 = 2 rows of 512B.
// global source granule (16B) XOR-swizzled by stage-row index.
#define P1_GLD(S, BUF)                                                       \
  do {                                                                       \
    _Pragma("unroll") for (int j_ = 0; j_ < 2; ++j_) {                       \
      const int jr_ = 4 * wv + 2 * j_;                                       \
      const int r_ = jr_ + (lane >> 5);                                      \
      const int g_ = lane & 31;                                              \
      const size_t gs_ = (size_t)(b * L_ + l0 + (S) * ST_ + r_) * E_ +       \
                         hcol0 + ((g_ ^ r_) << 2);                           \
      gld16(k + gs_, &kraw[BUF][jr_ * 128]);                                 \
      gld16(v + gs_, &vraw[BUF][jr_ * 128]);                                 \
    }                                                                        \
  } while (0)

// pack one 16-row stage (half of a K=32 tile) for this thread's head.
// tile K-pair col li = (S&1)*8 + lp2h.
#define P1_PACK(S, BUF)                                                      \
  do {                                                                       \
    const int la_ = 2 * lp2h, lb_ = la_ + 1;                                 \
    const float m0_ = msh[(S) * ST_ + la_];                                  \
    const float m1_ = msh[(S) * ST_ + lb_];                                  \
    const int lga_ = l0 + (S) * ST_ + la_;                                   \
    float s0_, c0_, s1_, c1_;                                                \
    __sincosf((float)(lga_ + 1) * DANG_, &s0_, &c0_);                        \
    __sincosf((float)(lga_ + 2) * DANG_, &s1_, &c1_);                        \
    const int li_ = ((S) & 1) * 8 + lp2h;                                    \
    _Pragma("unroll") for (int dj_ = 0; dj_ < 4; ++dj_) {                    \
      const int d_ = dg + 16 * dj_;                                          \
      const int c_ = hh * 64 + d_;                                           \
      const int G_ = c_ >> 2, su_ = c_ & 3;                                  \
      const float k0_ = kraw[BUF][la_ * 128 + ((G_ ^ la_) << 2) + su_];      \
      const float k1_ = kraw[BUF][lb_ * 128 + ((G_ ^ lb_) << 2) + su_];      \
      const float v0_ = vraw[BUF][la_ * 128 + ((G_ ^ la_) << 2) + su_];      \
      const float v1_ = vraw[BUF][lb_ * 128 + ((G_ ^ lb_) << 2) + su_];      \
      const float kr0_ = fmaxf(k0_, 0.f) * m0_;                              \
      const float kr1_ = fmaxf(k1_, 0.f) * m1_;                              \
      ka32[hh * (D2_ * 18) + d_ * 18 + li_] = pack2bf(kr0_ * s0_, kr1_ * s1_); \
      ka32[hh * (D2_ * 18) + (d_ + 64) * 18 + li_] =                         \
          pack2bf(kr0_ * c0_, kr1_ * c1_);                                   \
      vt32[hh * (D_ * 18) + d_ * 18 + li_] = pack2bf(v0_ * m0_, v1_ * m1_);  \
    }                                                                        \
  } while (0)

// MFMA one K=32 step for both heads: 2 x (8 real + 2 ones)
#define P1_MMA()                                                             \
  do {                                                                       \
    _Pragma("unroll") for (int hq_ = 0; hq_ < 2; ++hq_) {                    \
      short8 af_[2], bf_[4];                                                 \
      _Pragma("unroll") for (int dt_ = 0; dt_ < 2; ++dt_)                    \
          af_[dt_] = *(const short8*)&ka[hq_][(wv * 32 + dt_ * 16 + c_lo) *  \
                                                 36 + lp * 8];               \
      _Pragma("unroll") for (int mt_ = 0; mt_ < 4; ++mt_)                    \
          bf_[mt_] = *(const short8*)&vt[hq_][(mt_ * 16 + c_lo) * 36 +       \
                                              lp * 8];                       \
      _Pragma("unroll") for (int dt_ = 0; dt_ < 2; ++dt_) {                  \
        _Pragma("unroll") for (int mt_ = 0; mt_ < 4; ++mt_)                  \
            acc[hq_][dt_][mt_] = __builtin_amdgcn_mfma_f32_16x16x32_bf16(    \
                af_[dt_], bf_[mt_], acc[hq_][dt_][mt_], 0, 0, 0);            \
        acc5[hq_][dt_] = __builtin_amdgcn_mfma_f32_16x16x32_bf16(            \
            af_[dt_], bones, acc5[hq_][dt_], 0, 0, 0);                       \
      }                                                                      \
    }                                                                        \
  } while (0)

// 2-stage group: S even. bufs: S%3, (S+1)%3. Issues S+3 -> S%3, S+4 -> (S+1)%3.
#define P1_GROUP(S, I3, I4, VMN)                                             \
  do {                                                                       \
    P1_PACK((S), (S) % 3);                                                   \
    BAR_(); /* stage S raw consumed by all waves */                          \
    if (I3) P1_GLD((S) + 3, (S) % 3);                                        \
    P1_PACK((S) + 1, ((S) + 1) % 3);                                         \
    WAIT_LGKM0_();                                                           \
    BAR_(); /* tiles complete */                                             \
    if (I4) P1_GLD((S) + 4, ((S) + 1) % 3);                                  \
    P1_MMA();                                                                \
    if ((VMN) == 4) { WAIT_VM4_(); }                                         \
    else if ((VMN) == 0) { WAIT_VM0_(); }                                    \
    BAR_(); /* tiles consumed; next raw landed */                            \
  } while (0)

  // prologue: mask (wave0) + stages 0,1,2
  if (wv == 0) gld16(mask + (size_t)b * L_ + l0 + lane * 4, msh);
  P1_GLD(0, 0);
  P1_GLD(1, 1);
  P1_GLD(2, 2);
  WAIT_VM4_();  // drains mask + stages 0,1 (in-order retirement); keeps 2
  BAR_();

  P1_GROUP(0, 1, 1, 4);    // packs 0,1; issues 3,4; drains 2,3
  P1_GROUP(2, 1, 1, 4);    // packs 2,3; issues 5,6; drains 4,5
  P1_GROUP(4, 1, 1, 4);
  P1_GROUP(6, 1, 1, 4);
  P1_GROUP(8, 1, 1, 4);
  P1_GROUP(10, 1, 1, 4);   // issues 13,14; drains 12,13
  P1_GROUP(12, 1, 0, 0);   // packs 12,13; issues 15; drains all
  P1_GROUP(14, 0, 0, -1);  // packs 14,15; final MMA

  // write partial kv (fp32). C layout: row(d)=lp*4+r, col(m)=c_lo
#pragma unroll
  for (int hq = 0; hq < 2; ++hq) {
    const int n = 2 * p + hq;
    const size_t pbase = (size_t)(ch * N_ + n) * (D2_ * D_);
#pragma unroll
    for (int dt = 0; dt < 2; ++dt) {
      const int d = wv * 32 + dt * 16 + lp * 4;
#pragma unroll
      for (int mt = 0; mt < 4; ++mt) {
        const int mcol = mt * 16 + c_lo;
#pragma unroll
        for (int r = 0; r < 4; ++r)
          part_kv[pbase + (size_t)(d + r) * D_ + mcol] = acc[hq][dt][mt][r];
      }
    }
    if (c_lo == 0) {
#pragma unroll
      for (int dt = 0; dt < 2; ++dt)
#pragma unroll
        for (int r = 0; r < 4; ++r)
          part_ks[(size_t)(ch * N_ + n) * D2_ + wv * 32 + dt * 16 + lp * 4 +
                  r] = acc5[hq][dt][r];
    }
  }
}

// ---------------------------------------------------------------------------
// Reduce: sum chunk partials; emit kvT[n][m][d] bf16 + ksum fp32.
// 512 blocks (8 e-slices per head), f32x4 loads, small LDS transpose.
// ---------------------------------------------------------------------------
__global__ __launch_bounds__(256) void reduce_t(
    const float* __restrict__ part_kv, const float* __restrict__ part_ks,
    u16* __restrict__ kvt, float* __restrict__ ks) {
  __shared__ __align__(16) float tsh[16 * 68];
  const int bid = blockIdx.x;
  const int n = bid >> 3;
  const int sl = bid & 7;
  const int t = threadIdx.x;

  const int e0 = sl * 1024 + t * 4;  // covers d=sl*16..+16, m=0..63
  f32x4 s = (f32x4)0.f;
#pragma unroll
  for (int cc = 0; cc < CH_; ++cc)
    s += *(const f32x4*)&part_kv[(size_t)(cc * N_ + n) * (D2_ * D_) + e0];
  *(f32x4*)&tsh[(t >> 4) * 68 + (t & 15) * 4] = s;

  if (sl == 0 && t < D2_) {
    float ss = 0.f;
#pragma unroll
    for (int cc = 0; cc < CH_; ++cc)
      ss += part_ks[(size_t)(cc * N_ + n) * D2_ + t];
    ks[n * D2_ + t] = ss;
  }
  __syncthreads();

  // transpose out: thread -> m = t>>2, 4 consecutive d
  const int m = t >> 2;
  const int d4 = (t & 3) * 4;
  const u32 lo = pack2bf(tsh[(d4 + 0) * 68 + m], tsh[(d4 + 1) * 68 + m]);
  const u32 hi = pack2bf(tsh[(d4 + 2) * 68 + m], tsh[(d4 + 3) * 68 + m]);
  uint2 pk; pk.x = lo; pk.y = hi;
  *(uint2*)&kvt[(size_t)n * (D2_ * D_) + (size_t)m * D2_ + sl * 16 + d4] = pk;
}

// ---------------------------------------------------------------------------
// Phase 2 (MFMA): out[l][m] = z[l] * sum_d q_[l][d] * kv[d][m]
// Two 64-row l-chunks per block; kvt staged ONCE per block. All staging via
// global_load_lds width=16 (12 insts/wave), one barrier per block. Granules
// XOR-swizzled on the GLOBAL source and on the LDS reads (both-sides rule).
// z via 5th B-fragment whose column 0 is ksum.
// ---------------------------------------------------------------------------
__global__ __launch_bounds__(256, 3) void phase2_mfma(
    const float* __restrict__ q, const u16* __restrict__ kvt,
    const float* __restrict__ ks, float* __restrict__ out) {
  __shared__ __align__(16) float qsh[2 * 64 * 64];  // 32KB raw q, 2 chunks
  __shared__ __align__(16) u16 kbsh[64 * 128];      // 16KB kvt rows

  const int bid = blockIdx.x;
  const int n = bid & 63;
  const int g2 = bid >> 6;          // 0..31
  const int b = n >> 4, h = n & 15;
  const int t = threadIdx.x;
  const int wv = t >> 6, lane = t & 63;
  const int c_lo = lane & 15, quad = lane >> 4;
  const int l0 = g2 * 128;

  // ---- async staging: wave wv owns rows [wv*16, wv*16+16) of each tile ----
  const float* qbase = q + (size_t)(b * L_ + l0) * E_ + h * 64;
  const u16* kvbase = kvt + (size_t)n * (D2_ * D_);
  const int rsub = lane >> 4;  // row within one 1KB instruction
  const int g = lane & 15;     // physical 16B granule within row
#pragma unroll
  for (int j = 0; j < 4; ++j) {
    const int r = wv * 16 + j * 4 + rsub;
    const int sw = (g ^ (r & 15));
    gld16(kvbase + (size_t)r * D2_ + (sw << 3),
          kbsh + (wv * 16 + j * 4) * 128);
    gld16(qbase + (size_t)r * E_ + (sw << 2),
          qsh + (wv * 16 + j * 4) * 64);
    gld16(qbase + (size_t)(64 + r) * E_ + (sw << 2),
          qsh + 4096 + (wv * 16 + j * 4) * 64);
  }

  // ---- ksum B-fragments (register path, col 0 = ksum) ----
  const float* ksn = ks + n * D2_;
  short8 bks[4];
#pragma unroll
  for (int kk = 0; kk < 4; ++kk) {
    const f32x4 ka_ = *(const f32x4*)(ksn + kk * 32 + quad * 8);
    const f32x4 kb_ = *(const f32x4*)(ksn + kk * 32 + quad * 8 + 4);
    short8 tt = {0, 0, 0, 0, 0, 0, 0, 0};
    if (c_lo == 0) {
#pragma unroll
      for (int j = 0; j < 4; ++j) {
        tt[j] = bf1(ka_[j]);
        tt[j + 4] = bf1(kb_[j]);
      }
    }
    bks[kk] = tt;
  }

  __syncthreads();  // drains vmcnt(0): all global_load_lds landed

#pragma unroll
  for (int cc = 0; cc < 2; ++cc) {
    const int row = wv * 16 + c_lo;  // A-row within chunk
    const int glr = l0 + cc * 64 + row;
    float sv, cv;
    __sincosf((float)(glr + 1) * DANG_, &sv, &cv);

    // A-fragments from raw q LDS (swizzled reads)
    const float* qrow = qsh + cc * 4096 + row * 64;
    const int sw = row & 15;
    const f32x4 a0 = *(const f32x4*)(qrow + (((2 * quad) ^ sw) << 2));
    const f32x4 a1 = *(const f32x4*)(qrow + (((2 * quad + 1) ^ sw) << 2));
    const f32x4 a2 = *(const f32x4*)(qrow + (((8 + 2 * quad) ^ sw) << 2));
    const f32x4 a3 = *(const f32x4*)(qrow + (((9 + 2 * quad) ^ sw) << 2));

    short8 af[4];
#pragma unroll
    for (int j = 0; j < 4; ++j) {
      const float x0 = fmaxf(a0[j], 0.f);
      const float x1 = fmaxf(a1[j], 0.f);
      const float x2 = fmaxf(a2[j], 0.f);
      const float x3 = fmaxf(a3[j], 0.f);
      af[0][j] = bf1(x0 * sv); af[0][j + 4] = bf1(x1 * sv);
      af[1][j] = bf1(x2 * sv); af[1][j + 4] = bf1(x3 * sv);
      af[2][j] = bf1(x0 * cv); af[2][j + 4] = bf1(x1 * cv);
      af[3][j] = bf1(x2 * cv); af[3][j + 4] = bf1(x3 * cv);
    }

    f32x4 acc[4];
#pragma unroll
    for (int mt = 0; mt < 4; ++mt) acc[mt] = (f32x4)0.f;
    f32x4 acc5 = (f32x4)0.f;

#pragma unroll
    for (int kk = 0; kk < 4; ++kk) {
#pragma unroll
      for (int mt = 0; mt < 4; ++mt) {
        const int m = mt * 16 + c_lo;
        const short8 bfr = *(const short8*)
            &kbsh[m * 128 + (((kk * 4 + quad) ^ (m & 15)) << 3)];
        acc[mt] =
            __builtin_amdgcn_mfma_f32_16x16x32_bf16(af[kk], bfr, acc[mt], 0, 0, 0);
      }
      acc5 = __builtin_amdgcn_mfma_f32_16x16x32_bf16(af[kk], bks[kk], acc5, 0, 0, 0);
    }

    // epilogue: z from acc5 col 0 (lane quad*16), scale, store
#pragma unroll
    for (int r = 0; r < 4; ++r) {
      const float den = __shfl(acc5[r], quad * 16);
      const float z = 1.f / fmaxf(den, EPS_);
      const int gl = l0 + cc * 64 + wv * 16 + quad * 4 + r;
      const size_t ob = (size_t)n * (L_ * D_) + (size_t)gl * D_;
#pragma unroll
      for (int mt = 0; mt < 4; ++mt)
        out[ob + mt * 16 + c_lo] = acc[mt][r] * z;
    }
  }
}

// ---------------------------------------------------------------------------
extern "C" void kernel_launch(void* const* d_in, const int* in_sizes, int n_in,
                              void* d_out, int out_size, void* d_ws,
                              size_t ws_size, hipStream_t stream) {
  const float* q = (const float*)d_in[0];
  const float* k = (const float*)d_in[1];
  const float* v = (const float*)d_in[2];
  const float* mask = (const float*)d_in[3];
  float* out = (float*)d_out;

  float* part_kv = (float*)d_ws;                             // 16*64*8192 f32 = 33.5 MB
  float* part_ks = part_kv + (size_t)CH_ * N_ * D2_ * D_;    // 16*64*128 f32
  u16* kvt = (u16*)(part_ks + (size_t)CH_ * N_ * D2_);       // 64*8192 bf16 = 1 MB
  float* ks = (float*)(kvt + (size_t)N_ * D2_ * D_);         // 64*128 f32

  phase1_mfma<<<dim3(CH_ * 32), dim3(256), 0, stream>>>(k, v, mask, part_kv, part_ks);
  reduce_t<<<dim3(N_ * 8), dim3(256), 0, stream>>>(part_kv, part_ks, kvt, ks);
  phase2_mfma<<<dim3(N_ * 32), dim3(256), 0, stream>>>(q, kvt, ks, out);
}